// Round 1
// baseline (216.155 us; speedup 1.0000x reference)
//
#include <hip/hip_runtime.h>
#include <hip/hip_bf16.h>

#define E_TOT 200000
#define NZ 64
#define ATTR_D 768
#define KD 832          // 64 + 768
#define HID_D 128
#define NCLS 5

typedef __attribute__((ext_vector_type(8))) short short8;   // 8 bf16 (4 VGPRs)
typedef __attribute__((ext_vector_type(4))) float f32x4;    // MFMA accumulator

__device__ __forceinline__ unsigned pk2(float a, float b) {
    __hip_bfloat162 h = __float22bfloat162_rn(make_float2(a, b));
    return *reinterpret_cast<unsigned*>(&h);
}

// ---- prep: W1 [832][128] f32 -> W1t [128][832] bf16 (transposed, for contiguous B frags)
__global__ void prep_w1t(const float* __restrict__ W1, __hip_bfloat16* __restrict__ w1t) {
    int idx = blockIdx.x * 256 + threadIdx.x;
    if (idx >= HID_D * KD) return;
    int n = idx / KD;
    int k = idx - n * KD;
    w1t[idx] = __float2bfloat16(W1[(size_t)k * HID_D + n]);
}

// ---- main: 128 edges x 128 hid per block, K=832 in 26 steps of 32, fused MLP+softmax
__global__ __launch_bounds__(256) void gcn_main(
    const float* __restrict__ z, const int* __restrict__ ei,
    const float* __restrict__ attr, const __hip_bfloat16* __restrict__ w1t,
    const float* __restrict__ b1, const float* __restrict__ W2,
    const float* __restrict__ b2, float* __restrict__ out) {

    // LDS tiles as 16B chunks: row r has 4 chunks (32 bf16), physical chunk = c ^ ((r>>1)&3)
    __shared__ uint4 As4[128 * 4];
    __shared__ uint4 Bs4[128 * 4];

    const int t  = threadIdx.x;
    const int e0 = blockIdx.x * 128;

    // staging roles: 2 threads per row, each covers 16 elements (32B = 2 chunks)
    const int r    = t >> 1;      // 0..127 (edge row for A, hid row n for B)
    const int half = t & 1;
    const int e    = e0 + r;
    const bool ev  = (e < E_TOT);
    int si = 0, di = 0;
    if (ev) { si = ei[e]; di = ei[E_TOT + e]; }
    const float4* zs = reinterpret_cast<const float4*>(z + (size_t)si * NZ);
    const float4* zd = reinterpret_cast<const float4*>(z + (size_t)di * NZ);
    const float4* ar = reinterpret_cast<const float4*>(attr + (size_t)e * ATTR_D);
    const uint4* wrow = reinterpret_cast<const uint4*>(w1t + r * KD);  // 104 uint4 per row

    const int swz = (r >> 1) & 3;   // writer swizzle
    const int wc0 = half * 2;       // logical chunks wc0, wc0+1

    // compute roles
    const int wv   = t >> 6;        // wave 0..3 -> rows [wv*32, wv*32+32)
    const int lane = t & 63;
    const int g    = lane >> 4;     // k-group (chunk index for frag reads)
    const int c0   = lane & 15;

    f32x4 acc[2][8];
#pragma unroll
    for (int m = 0; m < 2; ++m)
#pragma unroll
        for (int f = 0; f < 8; ++f) acc[m][f] = (f32x4){0.f, 0.f, 0.f, 0.f};

    for (int kt = 0; kt < 26; ++kt) {
        const int k0 = kt * 32;

        // ---- stage B: Bs[n=r][0..32) = W1t[r][k0..k0+32)
        {
            const uint4* p = wrow + (k0 >> 3) + half * 2;   // uint4 = 8 bf16
            uint4 q0 = p[0];
            uint4 q1 = p[1];
            Bs4[(r << 2) + (wc0 ^ swz)]       = q0;
            Bs4[(r << 2) + ((wc0 + 1) ^ swz)] = q1;
        }
        // ---- stage A: joint[e][k0..k0+32) -> bf16
        {
            float4 x0, x1, x2, x3;
            if (kt < 2) {            // node_rep part: z[src]*z[dst], k in [0,64)
                int fo = (k0 + half * 16) >> 2;   // float4 index into 64-float z row
                if (ev) {
                    float4 s0 = zs[fo], s1 = zs[fo + 1], s2 = zs[fo + 2], s3 = zs[fo + 3];
                    float4 d0 = zd[fo], d1 = zd[fo + 1], d2 = zd[fo + 2], d3 = zd[fo + 3];
                    x0 = make_float4(s0.x * d0.x, s0.y * d0.y, s0.z * d0.z, s0.w * d0.w);
                    x1 = make_float4(s1.x * d1.x, s1.y * d1.y, s1.z * d1.z, s1.w * d1.w);
                    x2 = make_float4(s2.x * d2.x, s2.y * d2.y, s2.z * d2.z, s2.w * d2.w);
                    x3 = make_float4(s3.x * d3.x, s3.y * d3.y, s3.z * d3.z, s3.w * d3.w);
                } else {
                    x0 = x1 = x2 = x3 = make_float4(0.f, 0.f, 0.f, 0.f);
                }
            } else {                 // edge_attr part, k in [64,832)
                int fo = (k0 - 64 + half * 16) >> 2;
                if (ev) {
                    x0 = ar[fo]; x1 = ar[fo + 1]; x2 = ar[fo + 2]; x3 = ar[fo + 3];
                } else {
                    x0 = x1 = x2 = x3 = make_float4(0.f, 0.f, 0.f, 0.f);
                }
            }
            uint4 q0, q1;
            q0.x = pk2(x0.x, x0.y); q0.y = pk2(x0.z, x0.w);
            q0.z = pk2(x1.x, x1.y); q0.w = pk2(x1.z, x1.w);
            q1.x = pk2(x2.x, x2.y); q1.y = pk2(x2.z, x2.w);
            q1.z = pk2(x3.x, x3.y); q1.w = pk2(x3.z, x3.w);
            As4[(r << 2) + (wc0 ^ swz)]       = q0;
            As4[(r << 2) + ((wc0 + 1) ^ swz)] = q1;
        }
        __syncthreads();

        // ---- compute: per wave 2 M-frags x 8 N-frags
        {
            int row0 = wv * 32 + c0;        // m=0 edge row in tile
            int row1 = row0 + 16;           // m=1
            short8 a0 = *reinterpret_cast<const short8*>(&As4[(row0 << 2) + (g ^ ((row0 >> 1) & 3))]);
            short8 a1 = *reinterpret_cast<const short8*>(&As4[(row1 << 2) + (g ^ ((row1 >> 1) & 3))]);
            short8 bf[8];
#pragma unroll
            for (int f = 0; f < 8; ++f) {
                int n = f * 16 + c0;
                bf[f] = *reinterpret_cast<const short8*>(&Bs4[(n << 2) + (g ^ ((n >> 1) & 3))]);
            }
#pragma unroll
            for (int f = 0; f < 8; ++f) {
                acc[0][f] = __builtin_amdgcn_mfma_f32_16x16x32_bf16(a0, bf[f], acc[0][f], 0, 0, 0);
                acc[1][f] = __builtin_amdgcn_mfma_f32_16x16x32_bf16(a1, bf[f], acc[1][f], 0, 0, 0);
            }
        }
        __syncthreads();
    }

    // ---- epilogue: h = relu(acc + b1); logits = h @ W2 + b2; softmax; write
    float b1v[8], w2v[8][NCLS];
#pragma unroll
    for (int f = 0; f < 8; ++f) {
        int col = f * 16 + c0;
        b1v[f] = b1[col];
#pragma unroll
        for (int cc = 0; cc < NCLS; ++cc) w2v[f][cc] = W2[col * NCLS + cc];
    }
    float b2v[NCLS];
#pragma unroll
    for (int cc = 0; cc < NCLS; ++cc) b2v[cc] = b2[cc];

#pragma unroll
    for (int m = 0; m < 2; ++m) {
#pragma unroll
        for (int i = 0; i < 4; ++i) {
            float lg[NCLS] = {0.f, 0.f, 0.f, 0.f, 0.f};
#pragma unroll
            for (int f = 0; f < 8; ++f) {
                float h = acc[m][f][i] + b1v[f];
                h = fmaxf(h, 0.f);
#pragma unroll
                for (int cc = 0; cc < NCLS; ++cc) lg[cc] = fmaf(h, w2v[f][cc], lg[cc]);
            }
            // reduce the 16 lanes holding this row's 128 columns (lanes share g)
#pragma unroll
            for (int mask = 1; mask < 16; mask <<= 1) {
#pragma unroll
                for (int cc = 0; cc < NCLS; ++cc) lg[cc] += __shfl_xor(lg[cc], mask);
            }
#pragma unroll
            for (int cc = 0; cc < NCLS; ++cc) lg[cc] += b2v[cc];

            float mx = fmaxf(fmaxf(fmaxf(lg[0], lg[1]), fmaxf(lg[2], lg[3])), lg[4]);
            float q[NCLS];
            float s = 0.f;
#pragma unroll
            for (int cc = 0; cc < NCLS; ++cc) { q[cc] = __expf(lg[cc] - mx); s += q[cc]; }
            float inv = 1.0f / s;
            float num = (c0 == 0) ? q[0] : (c0 == 1) ? q[1] : (c0 == 2) ? q[2]
                      : (c0 == 3) ? q[3] : q[4];
            int rowl = wv * 32 + m * 16 + g * 4 + i;
            int eo = e0 + rowl;
            if (eo < E_TOT && c0 < NCLS) out[(size_t)eo * NCLS + c0] = num * inv;
        }
    }
}

extern "C" void kernel_launch(void* const* d_in, const int* in_sizes, int n_in,
                              void* d_out, int out_size, void* d_ws, size_t ws_size,
                              hipStream_t stream) {
    const float* z    = (const float*)d_in[0];
    const int*   ei   = (const int*)d_in[1];
    const float* attr = (const float*)d_in[2];
    const float* W1   = (const float*)d_in[3];
    const float* b1   = (const float*)d_in[4];
    const float* W2   = (const float*)d_in[5];
    const float* b2   = (const float*)d_in[6];
    float* out = (float*)d_out;
    __hip_bfloat16* w1t = (__hip_bfloat16*)d_ws;   // 128*832*2 = 212992 B

    prep_w1t<<<(HID_D * KD + 255) / 256, 256, 0, stream>>>(W1, w1t);
    const int nblk = (E_TOT + 127) / 128;   // 1563
    gcn_main<<<nblk, 256, 0, stream>>>(z, ei, attr, w1t, b1, W2, b2, out);
}